// Round 1
// baseline (225.661 us; speedup 1.0000x reference)
//
#include <hip/hip_runtime.h>

// ---------------------------------------------------------------------------
// TrajectoryAttention: x@Wq.T+bq / Wk / Wv -> RoPE(q,k) -> causal attn -> @Wo.T+bo
// B=2, T=2048, C=1024, H=16, D=64.  All matmuls in bf16 MFMA (fp32 accum).
// ---------------------------------------------------------------------------

typedef unsigned short u16;
typedef __bf16 bf16_t;
typedef bf16_t bf16x8 __attribute__((ext_vector_type(8)));
typedef float f32x4 __attribute__((ext_vector_type(4)));

#define T_SEQ 2048
#define C_DIM 1024

__device__ __forceinline__ u16 f2bf(float f) {
  union { float f; unsigned u; } v; v.f = f;
  return (u16)((v.u + 0x7FFFu + ((v.u >> 16) & 1u)) >> 16);  // RNE
}

__device__ __forceinline__ void gload_lds16(const void* g, void* l) {
  __builtin_amdgcn_global_load_lds(
      (const __attribute__((address_space(1))) void*)g,
      (__attribute__((address_space(3))) void*)l, 16, 0, 0);
}

// ---------------------------------------------------------------------------
// fp32 -> bf16 convert, 4 elems/thread
__global__ __launch_bounds__(256) void cvt_kernel(const float* __restrict__ in,
                                                  u16* __restrict__ out, int n4) {
  int i = blockIdx.x * blockDim.x + threadIdx.x;
  if (i < n4) {
    float4 f = ((const float4*)in)[i];
    ushort4 o;
    o.x = f2bf(f.x); o.y = f2bf(f.y); o.z = f2bf(f.z); o.w = f2bf(f.w);
    ((ushort4*)out)[i] = o;
  }
}

// RoPE table: tab[t*64 + i] = cos(t * 10000^(-i/32)), tab[t*64+32+i] = sin(...)
__global__ __launch_bounds__(256) void rope_table_kernel(float* __restrict__ tab) {
  int idx = blockIdx.x * blockDim.x + threadIdx.x;  // T*32 = 65536
  int t = idx >> 5, i = idx & 31;
  float freq = powf(10000.0f, -(float)i * (1.0f / 32.0f));
  float a = (float)t * freq;
  tab[t * 64 + i] = cosf(a);
  tab[t * 64 + 32 + i] = sinf(a);
}

// ---------------------------------------------------------------------------
// Shared GEMM mainloop: C[128x128] = A[128xK] * Bt[128xK]^T, K=1024, BK=64.
// LDS rows are 128 B; staging pre-swizzles the GLOBAL source k-chunk
// (slot s holds k-chunk s^(row&7)) so swizzled ds_read_b128 is bank-spread.
__device__ __forceinline__ void gemm_tile(const u16* __restrict__ A,
                                          const u16* __restrict__ Bt,
                                          int m0, int n0, u16* lA, u16* lB,
                                          f32x4 acc[4][4]) {
  const int tid = threadIdx.x;
  const int l = tid & 63;
  const int wr = tid >> 7, wc = (tid >> 6) & 1;

#pragma unroll
  for (int m = 0; m < 4; ++m)
#pragma unroll
    for (int n = 0; n < 4; ++n)
      acc[m][n] = (f32x4){0.f, 0.f, 0.f, 0.f};

  for (int k0 = 0; k0 < 1024; k0 += 64) {
#pragma unroll
    for (int r = 0; r < 4; ++r) {  // A tile: 128 rows x 8 slots of 16B
      int ch = r * 256 + tid;
      int row = ch >> 3, s = ch & 7;
      gload_lds16(A + (size_t)(m0 + row) * 1024 + k0 + ((s ^ (row & 7)) << 3),
                  lA + ch * 8);
    }
#pragma unroll
    for (int r = 0; r < 4; ++r) {
      int ch = r * 256 + tid;
      int row = ch >> 3, s = ch & 7;
      gload_lds16(Bt + (size_t)(n0 + row) * 1024 + k0 + ((s ^ (row & 7)) << 3),
                  lB + ch * 8);
    }
    __syncthreads();  // drains vmcnt before any ds_read

#pragma unroll
    for (int kk = 0; kk < 2; ++kk) {
      bf16x8 af[4], bf[4];
#pragma unroll
      for (int m = 0; m < 4; ++m) {
        int row = wr * 64 + m * 16 + (l & 15);
        int slot = (kk * 4 + (l >> 4)) ^ (row & 7);
        af[m] = *(const bf16x8*)(lA + row * 64 + slot * 8);
      }
#pragma unroll
      for (int n = 0; n < 4; ++n) {
        int row = wc * 64 + n * 16 + (l & 15);
        int slot = (kk * 4 + (l >> 4)) ^ (row & 7);
        bf[n] = *(const bf16x8*)(lB + row * 64 + slot * 8);
      }
#pragma unroll
      for (int m = 0; m < 4; ++m)
#pragma unroll
        for (int n = 0; n < 4; ++n)
          acc[m][n] =
              __builtin_amdgcn_mfma_f32_16x16x32_bf16(af[m], bf[n], acc[m][n], 0, 0, 0);
    }
    __syncthreads();
  }
}

// ---------------------------------------------------------------------------
// QKV projection + bias + RoPE.  z=0:Q  z=1:K  (RoPE, [B,H,T,D])  z=2:V ([B,H,D,T])
__global__ __launch_bounds__(256) void qkv_kernel(
    const u16* __restrict__ xb, const u16* __restrict__ Wqb,
    const u16* __restrict__ Wkb, const u16* __restrict__ Wvb,
    const float* __restrict__ bq, const float* __restrict__ bk,
    const float* __restrict__ bv, const float* __restrict__ tab,
    u16* __restrict__ Q, u16* __restrict__ Kr, u16* __restrict__ Vt) {
  __shared__ __align__(16) u16 lA[128 * 64];
  __shared__ __align__(16) u16 lB[128 * 64];
  const int z = blockIdx.z;
  const u16* W = (z == 0) ? Wqb : ((z == 1) ? Wkb : Wvb);
  const float* bias = (z == 0) ? bq : ((z == 1) ? bk : bv);
  const int m0 = blockIdx.y * 128, n0 = blockIdx.x * 128;

  f32x4 acc[4][4];
  gemm_tile(xb, W, m0, n0, lA, lB, acc);

  const int tid = threadIdx.x, l = tid & 63;
  const int wr = tid >> 7, wc = (tid >> 6) & 1;
#pragma unroll
  for (int m = 0; m < 4; ++m)
#pragma unroll
    for (int n = 0; n < 4; ++n)
#pragma unroll
      for (int jr = 0; jr < 4; ++jr) {
        int gr = m0 + wr * 64 + m * 16 + ((l >> 4) << 2) + jr;  // token row
        int gc = n0 + wc * 64 + n * 16 + (l & 15);              // channel
        int b = gr >> 11, t = gr & 2047;
        int h = gc >> 6, d = gc & 63;
        float val = acc[m][n][jr] + bias[gc];
        if (z == 2) {
          // V transposed: Vt[((b*16+h)*64 + d)*2048 + t]
          Vt[(((size_t)((b * 16 + h) * 64 + d)) << 11) + t] = f2bf(val);
        } else {
          float p = acc[m][n ^ 2][jr] + bias[gc ^ 32];  // partner channel d^32
          float cs = tab[t * 64 + (d & 31)];
          float sn = tab[t * 64 + 32 + (d & 31)];
          float rot = (d < 32) ? -p : p;
          float o = val * cs + rot * sn;
          u16* dst = (z == 0) ? Q : Kr;
          dst[((((size_t)(b * 16 + h)) << 11) + t) * 64 + d] = f2bf(o);
        }
      }
}

// ---------------------------------------------------------------------------
// Flash attention (causal). 1 block = (qb, bh): 64 q-rows, 4 waves x 16 rows.
// K: [B,H,T,D] bf16; Vt: [B,H,D,T] bf16. Out: bf16 [B,T,C] (heads re-merged).
__global__ __launch_bounds__(256) void attn_kernel(const u16* __restrict__ Q,
                                                   const u16* __restrict__ K,
                                                   const u16* __restrict__ Vt,
                                                   u16* __restrict__ out) {
  __shared__ __align__(16) u16 lK[64 * 64];
  __shared__ __align__(16) u16 lV[64 * 64];
  __shared__ __align__(16) u16 lP[4][16 * 64];
  const int tid = threadIdx.x, l = tid & 63, w = tid >> 6;
  const int qb = blockIdx.x, bh = blockIdx.y;
  const int b = bh >> 4, h = bh & 15;

  // Q fragments (held whole kernel): rows w*16..+15 of this q-block
  const int qrow = qb * 64 + w * 16 + (l & 15);
  const u16* qptr = Q + ((((size_t)bh) << 11) + qrow) * 64 + ((l >> 4) << 3);
  bf16x8 aq0 = *(const bf16x8*)(qptr);
  bf16x8 aq1 = *(const bf16x8*)(qptr + 32);

  f32x4 o[4];
#pragma unroll
  for (int n = 0; n < 4; ++n) o[n] = (f32x4){0.f, 0.f, 0.f, 0.f};
  float mi[4], li[4];
#pragma unroll
  for (int jr = 0; jr < 4; ++jr) { mi[jr] = -1e30f; li[jr] = 0.f; }

  const int ig = qb * 64 + w * 16 + ((l >> 4) << 2);  // + jr = global q row

  for (int kv0 = 0; kv0 <= qb * 64; kv0 += 64) {
#pragma unroll
    for (int r = 0; r < 2; ++r) {  // stage K tile [64 kv][64 d], swizzled
      int ch = r * 256 + tid;
      int row = ch >> 3, s = ch & 7;
      gload_lds16(K + ((((size_t)bh) << 11) + kv0 + row) * 64 + ((s ^ (row & 7)) << 3),
                  lK + ch * 8);
    }
#pragma unroll
    for (int r = 0; r < 2; ++r) {  // stage Vt tile [64 d][64 kv], swizzled
      int ch = r * 256 + tid;
      int row = ch >> 3, s = ch & 7;  // row = d
      gload_lds16(Vt + ((((size_t)bh) * 64 + row) << 11) + kv0 + ((s ^ (row & 7)) << 3),
                  lV + ch * 8);
    }
    __syncthreads();

    // S = Q K^T  (16 q-rows x 64 kv)
    f32x4 sacc[4];
#pragma unroll
    for (int n = 0; n < 4; ++n) sacc[n] = (f32x4){0.f, 0.f, 0.f, 0.f};
#pragma unroll
    for (int n = 0; n < 4; ++n) {
      int kv = n * 16 + (l & 15);
      int sl0 = ((l >> 4)) ^ (kv & 7);
      int sl1 = (4 + (l >> 4)) ^ (kv & 7);
      bf16x8 k0 = *(const bf16x8*)(lK + kv * 64 + sl0 * 8);
      bf16x8 k1 = *(const bf16x8*)(lK + kv * 64 + sl1 * 8);
      sacc[n] = __builtin_amdgcn_mfma_f32_16x16x32_bf16(aq0, k0, sacc[n], 0, 0, 0);
      sacc[n] = __builtin_amdgcn_mfma_f32_16x16x32_bf16(aq1, k1, sacc[n], 0, 0, 0);
    }

    // online softmax (rows live in 16-lane groups; reduce over l&15)
    float sv[4][4], mt[4];
#pragma unroll
    for (int jr = 0; jr < 4; ++jr) mt[jr] = -1e30f;
#pragma unroll
    for (int n = 0; n < 4; ++n) {
      int jg = kv0 + n * 16 + (l & 15);
#pragma unroll
      for (int jr = 0; jr < 4; ++jr) {
        float x = sacc[n][jr] * 0.125f;           // 1/sqrt(64)
        if (jg > ig + jr) x = -1e30f;             // causal mask
        sv[n][jr] = x;
        mt[jr] = fmaxf(mt[jr], x);
      }
    }
#pragma unroll
    for (int off = 1; off < 16; off <<= 1)
#pragma unroll
      for (int jr = 0; jr < 4; ++jr) mt[jr] = fmaxf(mt[jr], __shfl_xor(mt[jr], off, 64));
    float al[4];
#pragma unroll
    for (int jr = 0; jr < 4; ++jr) {
      float mn = fmaxf(mi[jr], mt[jr]);
      al[jr] = __expf(mi[jr] - mn);
      mi[jr] = mn;
    }
    float rs[4] = {0.f, 0.f, 0.f, 0.f};
#pragma unroll
    for (int n = 0; n < 4; ++n)
#pragma unroll
      for (int jr = 0; jr < 4; ++jr) {
        float p = __expf(sv[n][jr] - mi[jr]);
        rs[jr] += p;
        int i = ((l >> 4) << 2) + jr;
        int j = n * 16 + (l & 15);
        lP[w][(i * 64 + j) ^ ((i & 7) << 3)] = f2bf(p);  // swizzled P store
      }
#pragma unroll
    for (int off = 1; off < 16; off <<= 1)
#pragma unroll
      for (int jr = 0; jr < 4; ++jr) rs[jr] += __shfl_xor(rs[jr], off, 64);
#pragma unroll
    for (int jr = 0; jr < 4; ++jr) li[jr] = li[jr] * al[jr] + rs[jr];
#pragma unroll
    for (int n = 0; n < 4; ++n)
#pragma unroll
      for (int jr = 0; jr < 4; ++jr) o[n][jr] *= al[jr];

    // O += P V   (P from per-wave LDS, V^T from shared LDS)
#pragma unroll
    for (int kk = 0; kk < 2; ++kk) {
      int i = l & 15;
      int cslot = kk * 4 + (l >> 4);
      bf16x8 ap = *(const bf16x8*)(&lP[w][0] + ((i * 64 + cslot * 8) ^ ((i & 7) << 3)));
#pragma unroll
      for (int nd = 0; nd < 4; ++nd) {
        int d = nd * 16 + (l & 15);
        int slot = cslot ^ (d & 7);
        bf16x8 bv_ = *(const bf16x8*)(lV + d * 64 + slot * 8);
        o[nd] = __builtin_amdgcn_mfma_f32_16x16x32_bf16(ap, bv_, o[nd], 0, 0, 0);
      }
    }
    __syncthreads();
  }

  // write attn output bf16, heads merged: [B,T,C]
#pragma unroll
  for (int nd = 0; nd < 4; ++nd)
#pragma unroll
    for (int jr = 0; jr < 4; ++jr) {
      int t = qb * 64 + w * 16 + ((l >> 4) << 2) + jr;
      int cc = h * 64 + nd * 16 + (l & 15);
      out[((size_t)(b * 2048 + t)) * 1024 + cc] = f2bf(o[nd][jr] / li[jr]);
    }
}

// ---------------------------------------------------------------------------
// Output projection: out = attn @ Wo^T + bo  (fp32 output)
__global__ __launch_bounds__(256) void outproj_kernel(const u16* __restrict__ attn,
                                                      const u16* __restrict__ Wob,
                                                      const float* __restrict__ bo,
                                                      float* __restrict__ out) {
  __shared__ __align__(16) u16 lA[128 * 64];
  __shared__ __align__(16) u16 lB[128 * 64];
  const int m0 = blockIdx.y * 128, n0 = blockIdx.x * 128;
  f32x4 acc[4][4];
  gemm_tile(attn, Wob, m0, n0, lA, lB, acc);
  const int tid = threadIdx.x, l = tid & 63;
  const int wr = tid >> 7, wc = (tid >> 6) & 1;
#pragma unroll
  for (int m = 0; m < 4; ++m)
#pragma unroll
    for (int n = 0; n < 4; ++n)
#pragma unroll
      for (int jr = 0; jr < 4; ++jr) {
        int gr = m0 + wr * 64 + m * 16 + ((l >> 4) << 2) + jr;
        int gc = n0 + wc * 64 + n * 16 + (l & 15);
        out[(size_t)gr * 1024 + gc] = acc[m][n][jr] + bo[gc];
      }
}

// ---------------------------------------------------------------------------
extern "C" void kernel_launch(void* const* d_in, const int* in_sizes, int n_in,
                              void* d_out, int out_size, void* d_ws, size_t ws_size,
                              hipStream_t stream) {
  const float* x  = (const float*)d_in[0];
  const float* Wq = (const float*)d_in[1];
  const float* bq = (const float*)d_in[2];
  const float* Wk = (const float*)d_in[3];
  const float* bk = (const float*)d_in[4];
  const float* Wv = (const float*)d_in[5];
  const float* bv = (const float*)d_in[6];
  const float* Wo = (const float*)d_in[7];
  const float* bo = (const float*)d_in[8];
  float* out = (float*)d_out;

  char* ws = (char*)d_ws;
  u16* xb  = (u16*)(ws);                          // 8 MB  x bf16 [4096][1024]
  u16* Wqb = (u16*)(ws + (8ull << 20));           // 2 MB
  u16* Wkb = (u16*)(ws + (10ull << 20));          // 2 MB
  u16* Wvb = (u16*)(ws + (12ull << 20));          // 2 MB
  u16* Wob = (u16*)(ws + (14ull << 20));          // 2 MB
  u16* Qr  = (u16*)(ws + (16ull << 20));          // 8 MB  [B,H,T,D]
  u16* Kr  = (u16*)(ws + (24ull << 20));          // 8 MB  [B,H,T,D]
  u16* Vt  = (u16*)(ws + (32ull << 20));          // 8 MB  [B,H,D,T]
  u16* At  = (u16*)(ws + (40ull << 20));          // 8 MB  attn out bf16 [B,T,C]
  float* tab = (float*)(ws + (48ull << 20));      // 512 KB rope table

  cvt_kernel<<<dim3(4096), dim3(256), 0, stream>>>(x, xb, 1048576);
  cvt_kernel<<<dim3(1024), dim3(256), 0, stream>>>(Wq, Wqb, 262144);
  cvt_kernel<<<dim3(1024), dim3(256), 0, stream>>>(Wk, Wkb, 262144);
  cvt_kernel<<<dim3(1024), dim3(256), 0, stream>>>(Wv, Wvb, 262144);
  cvt_kernel<<<dim3(1024), dim3(256), 0, stream>>>(Wo, Wob, 262144);
  rope_table_kernel<<<dim3(256), dim3(256), 0, stream>>>(tab);

  qkv_kernel<<<dim3(8, 32, 3), dim3(256), 0, stream>>>(xb, Wqb, Wkb, Wvb, bq, bk, bv,
                                                       tab, Qr, Kr, Vt);
  attn_kernel<<<dim3(32, 32), dim3(256), 0, stream>>>(Qr, Kr, Vt, At);
  outproj_kernel<<<dim3(8, 32), dim3(256), 0, stream>>>(At, Wob, bo, out);
}

// Round 2
// 180.289 us; speedup vs baseline: 1.2517x; 1.2517x over previous
//
#include <hip/hip_runtime.h>

// ---------------------------------------------------------------------------
// TrajectoryAttention: x@Wq.T+bq / Wk / Wv -> RoPE(q,k) -> causal attn -> @Wo.T+bo
// B=2, T=2048, C=1024, H=16, D=64.  All matmuls bf16 MFMA (fp32 accum).
// Attention: swapped-operand 32x32 flash structure, P fully in registers.
// ---------------------------------------------------------------------------

typedef unsigned short u16;
typedef unsigned int u32;
typedef __bf16 bf16_t;
typedef bf16_t bf16x8 __attribute__((ext_vector_type(8)));
typedef float f32x4 __attribute__((ext_vector_type(4)));
typedef float f32x16 __attribute__((ext_vector_type(16)));

__device__ __forceinline__ u16 f2bf(float f) {
  union { float f; unsigned u; } v; v.f = f;
  return (u16)((v.u + 0x7FFFu + ((v.u >> 16) & 1u)) >> 16);  // RNE
}

__device__ __forceinline__ void gload_lds16(const void* g, void* l) {
  __builtin_amdgcn_global_load_lds(
      (const __attribute__((address_space(1))) void*)g,
      (__attribute__((address_space(3))) void*)l, 16, 0, 0);
}

// ---------------------------------------------------------------------------
__global__ __launch_bounds__(256) void cvt_kernel(const float* __restrict__ in,
                                                  u16* __restrict__ out, int n4) {
  int i = blockIdx.x * blockDim.x + threadIdx.x;
  if (i < n4) {
    float4 f = ((const float4*)in)[i];
    ushort4 o;
    o.x = f2bf(f.x); o.y = f2bf(f.y); o.z = f2bf(f.z); o.w = f2bf(f.w);
    ((ushort4*)out)[i] = o;
  }
}

__global__ __launch_bounds__(256) void rope_table_kernel(float* __restrict__ tab) {
  int idx = blockIdx.x * blockDim.x + threadIdx.x;  // T*32 = 65536
  int t = idx >> 5, i = idx & 31;
  float freq = powf(10000.0f, -(float)i * (1.0f / 32.0f));
  float a = (float)t * freq;
  tab[t * 64 + i] = cosf(a);
  tab[t * 64 + 32 + i] = sinf(a);
}

// ---------------------------------------------------------------------------
// Shared GEMM mainloop: C[128x128] = A[128xK] * Bt[128xK]^T, K=1024, BK=64.
__device__ __forceinline__ void gemm_tile(const u16* __restrict__ A,
                                          const u16* __restrict__ Bt,
                                          int m0, int n0, u16* lA, u16* lB,
                                          f32x4 acc[4][4]) {
  const int tid = threadIdx.x;
  const int l = tid & 63;
  const int wr = tid >> 7, wc = (tid >> 6) & 1;

#pragma unroll
  for (int m = 0; m < 4; ++m)
#pragma unroll
    for (int n = 0; n < 4; ++n)
      acc[m][n] = (f32x4){0.f, 0.f, 0.f, 0.f};

  for (int k0 = 0; k0 < 1024; k0 += 64) {
#pragma unroll
    for (int r = 0; r < 4; ++r) {
      int ch = r * 256 + tid;
      int row = ch >> 3, s = ch & 7;
      gload_lds16(A + (size_t)(m0 + row) * 1024 + k0 + ((s ^ (row & 7)) << 3),
                  lA + ch * 8);
    }
#pragma unroll
    for (int r = 0; r < 4; ++r) {
      int ch = r * 256 + tid;
      int row = ch >> 3, s = ch & 7;
      gload_lds16(Bt + (size_t)(n0 + row) * 1024 + k0 + ((s ^ (row & 7)) << 3),
                  lB + ch * 8);
    }
    __syncthreads();

#pragma unroll
    for (int kk = 0; kk < 2; ++kk) {
      bf16x8 af[4], bf[4];
#pragma unroll
      for (int m = 0; m < 4; ++m) {
        int row = wr * 64 + m * 16 + (l & 15);
        int slot = (kk * 4 + (l >> 4)) ^ (row & 7);
        af[m] = *(const bf16x8*)(lA + row * 64 + slot * 8);
      }
#pragma unroll
      for (int n = 0; n < 4; ++n) {
        int row = wc * 64 + n * 16 + (l & 15);
        int slot = (kk * 4 + (l >> 4)) ^ (row & 7);
        bf[n] = *(const bf16x8*)(lB + row * 64 + slot * 8);
      }
#pragma unroll
      for (int m = 0; m < 4; ++m)
#pragma unroll
        for (int n = 0; n < 4; ++n)
          acc[m][n] =
              __builtin_amdgcn_mfma_f32_16x16x32_bf16(af[m], bf[n], acc[m][n], 0, 0, 0);
    }
    __syncthreads();
  }
}

// ---------------------------------------------------------------------------
// QKV projection + bias + RoPE.  z=0:Q (scaled by 1/8)  z=1:K  z=2:V ([B,H,D,T])
__global__ __launch_bounds__(256) void qkv_kernel(
    const u16* __restrict__ xb, const u16* __restrict__ Wqb,
    const u16* __restrict__ Wkb, const u16* __restrict__ Wvb,
    const float* __restrict__ bq, const float* __restrict__ bk,
    const float* __restrict__ bv, const float* __restrict__ tab,
    u16* __restrict__ Q, u16* __restrict__ Kr, u16* __restrict__ Vt) {
  __shared__ __align__(16) u16 lA[128 * 64];
  __shared__ __align__(16) u16 lB[128 * 64];
  const int z = blockIdx.z;
  const u16* W = (z == 0) ? Wqb : ((z == 1) ? Wkb : Wvb);
  const float* bias = (z == 0) ? bq : ((z == 1) ? bk : bv);
  const int m0 = blockIdx.y * 128, n0 = blockIdx.x * 128;

  f32x4 acc[4][4];
  gemm_tile(xb, W, m0, n0, lA, lB, acc);

  const int tid = threadIdx.x, l = tid & 63;
  const int wr = tid >> 7, wc = (tid >> 6) & 1;
#pragma unroll
  for (int m = 0; m < 4; ++m)
#pragma unroll
    for (int n = 0; n < 4; ++n)
#pragma unroll
      for (int jr = 0; jr < 4; ++jr) {
        int gr = m0 + wr * 64 + m * 16 + ((l >> 4) << 2) + jr;  // token row
        int gc = n0 + wc * 64 + n * 16 + (l & 15);              // channel
        int b = gr >> 11, t = gr & 2047;
        int h = gc >> 6, d = gc & 63;
        float val = acc[m][n][jr] + bias[gc];
        if (z == 2) {
          Vt[(((size_t)((b * 16 + h) * 64 + d)) << 11) + t] = f2bf(val);
        } else {
          float p = acc[m][n ^ 2][jr] + bias[gc ^ 32];  // partner channel d^32
          float cs = tab[t * 64 + (d & 31)];
          float sn = tab[t * 64 + 32 + (d & 31)];
          float rot = (d < 32) ? -p : p;
          float o = val * cs + rot * sn;
          if (z == 0) o *= 0.125f;  // fold 1/sqrt(64) into Q
          u16* dst = (z == 0) ? Q : Kr;
          dst[((((size_t)(b * 16 + h)) << 11) + t) * 64 + d] = f2bf(o);
        }
      }
}

// ---------------------------------------------------------------------------
// Flash attention (causal), swapped-operand 32x32 MFMA, P in registers.
// Block = 128 threads = 2 warps; warp w owns q rows [qt*64+w*32, +32).
// Lane's q = q0w + (lane&31); hl = lane>>5 splits k-dim / C-rows.
__global__ __launch_bounds__(128) void attn_kernel(const u16* __restrict__ Q,
                                                   const u16* __restrict__ K,
                                                   const u16* __restrict__ Vt,
                                                   u16* __restrict__ out) {
  __shared__ __align__(16) u16 lK[64 * 64];
  __shared__ __align__(16) u16 lV[64 * 64];
  const int tid = threadIdx.x, l = tid & 63, w = tid >> 6;
  // XCD-grouped decode: XCD x handles bh in {4x..4x+3} (K/V/Q fit its L2)
  const int n = blockIdx.x;
  const int xcd = n & 7, j = n >> 3;
  const int bh = xcd * 4 + (j & 3);   // 0..31
  const int qt = j >> 2;              // 0..31
  const int b = bh >> 4, h = bh & 15;
  const int lq = l & 31, hl = l >> 5;
  const int q0w = qt * 64 + w * 32;
  const int qg = q0w + lq;  // this lane's global q row

  // Q fragments held in registers: qf[kd] = Q[qg][kd*16 + hl*8 .. +8]
  const u16* qbase = Q + ((((size_t)bh) << 11) + qg) * 64 + hl * 8;
  bf16x8 qf[4];
#pragma unroll
  for (int kd = 0; kd < 4; ++kd) qf[kd] = *(const bf16x8*)(qbase + kd * 16);

  const f32x16 z16 = {0.f, 0.f, 0.f, 0.f, 0.f, 0.f, 0.f, 0.f,
                      0.f, 0.f, 0.f, 0.f, 0.f, 0.f, 0.f, 0.f};
  f32x16 oacc[2];  // O^T: rows d = dblk*32 + (r&3)+8*(r>>2)+4*hl, col q = lq
  oacc[0] = z16; oacc[1] = z16;
  float mi = -1e30f, li = 0.f;

  const int nt = qt + 1;
  for (int it = 0; it < nt; ++it) {
    const int kv0 = it * 64;
    // ---- stage K [64 kv][64 d] and Vt [64 d][64 kv], slot-swizzled ----
#pragma unroll
    for (int r = 0; r < 4; ++r) {
      int ch = r * 128 + tid;
      int row = ch >> 3, s = ch & 7;
      gload_lds16(K + ((((size_t)bh) << 11) + kv0 + row) * 64 + ((s ^ (row & 7)) << 3),
                  lK + ch * 8);
    }
#pragma unroll
    for (int r = 0; r < 4; ++r) {
      int ch = r * 128 + tid;
      int row = ch >> 3, s = ch & 7;  // row = d
      gload_lds16(Vt + ((((size_t)bh) * 64 + row) << 11) + kv0 + ((s ^ (row & 7)) << 3),
                  lV + ch * 8);
    }
    __syncthreads();

    // ---- S^T = K Q^T : sacc[g] rows = kv (32g..), cols = q ----
    f32x16 sacc[2];
    sacc[0] = z16; sacc[1] = z16;
#pragma unroll
    for (int g = 0; g < 2; ++g) {
      int row = g * 32 + lq;
      int sw = row & 7;
#pragma unroll
      for (int kd = 0; kd < 4; ++kd) {
        bf16x8 kf = *(const bf16x8*)(lK + row * 64 + (((kd * 2 + hl) ^ sw) << 3));
        sacc[g] = __builtin_amdgcn_mfma_f32_32x32x16_bf16(kf, qf[kd], sacc[g], 0, 0, 0);
      }
    }

    // ---- causal mask (only final tile of this warp triggers) ----
    if (kv0 + 63 > q0w) {
#pragma unroll
      for (int g = 0; g < 2; ++g)
#pragma unroll
        for (int r = 0; r < 16; ++r) {
          int kv = kv0 + g * 32 + (r & 3) + ((r >> 2) << 3) + hl * 4;
          if (kv > qg) sacc[g][r] = -1e30f;
        }
    }

    // ---- online softmax: lane holds 32 of 64 kv for its q; partner has rest
    float mx[16];
#pragma unroll
    for (int r = 0; r < 16; ++r) mx[r] = fmaxf(sacc[0][r], sacc[1][r]);
#pragma unroll
    for (int s = 8; s > 0; s >>= 1)
#pragma unroll
      for (int r = 0; r < s; ++r) mx[r] = fmaxf(mx[r], mx[r + s]);
    float mt = fmaxf(mx[0], __shfl_xor(mx[0], 32, 64));
    float mn = fmaxf(mi, mt);
    float al = __expf(mi - mn);
    mi = mn;
#pragma unroll
    for (int g = 0; g < 2; ++g)
#pragma unroll
      for (int r = 0; r < 16; ++r) sacc[g][r] = __expf(sacc[g][r] - mn);
    float sm[16];
#pragma unroll
    for (int r = 0; r < 16; ++r) sm[r] = sacc[0][r] + sacc[1][r];
#pragma unroll
    for (int s = 8; s > 0; s >>= 1)
#pragma unroll
      for (int r = 0; r < s; ++r) sm[r] += sm[r + s];
    float rs = sm[0] + __shfl_xor(sm[0], 32, 64);
    li = li * al + rs;
#pragma unroll
    for (int dblk = 0; dblk < 2; ++dblk)
#pragma unroll
      for (int r = 0; r < 16; ++r) oacc[dblk][r] *= al;

    // ---- P -> bf16 pairs; build PV B-fragments via cross-half exchange ----
    u32 pw[2][8], px[2][8];
#pragma unroll
    for (int g = 0; g < 2; ++g)
#pragma unroll
      for (int i = 0; i < 8; ++i) {
        union { bf16_t h2[2]; u32 u; } pk;
        pk.h2[0] = (bf16_t)sacc[g][2 * i];
        pk.h2[1] = (bf16_t)sacc[g][2 * i + 1];
        pw[g][i] = pk.u;
      }
#pragma unroll
    for (int g = 0; g < 2; ++g)
#pragma unroll
      for (int i = 0; i < 8; ++i)
        px[g][i] = (u32)__shfl_xor((int)pw[g][i], 32, 64);

    bf16x8 pfrag[4];  // B-frag for kv chunk km*16: col=q, k=kv (hl*8+j)
#pragma unroll
    for (int km = 0; km < 4; ++km) {
      const int g = km >> 1, o = (km & 1) * 4;
      union { u32 u[4]; bf16x8 v; } f;
      f.u[0] = hl ? px[g][o + 2] : pw[g][o + 0];
      f.u[1] = hl ? px[g][o + 3] : pw[g][o + 1];
      f.u[2] = hl ? pw[g][o + 2] : px[g][o + 0];
      f.u[3] = hl ? pw[g][o + 3] : px[g][o + 1];
      pfrag[km] = f.v;
    }

    // ---- O^T += V^T P^T : A = Vt rows d, k = kv; B = P fragment ----
#pragma unroll
    for (int dblk = 0; dblk < 2; ++dblk) {
      int row = dblk * 32 + lq;
      int sw = row & 7;
#pragma unroll
      for (int km = 0; km < 4; ++km) {
        bf16x8 vf = *(const bf16x8*)(lV + row * 64 + (((km * 2 + hl) ^ sw) << 3));
        oacc[dblk] = __builtin_amdgcn_mfma_f32_32x32x16_bf16(vf, pfrag[km], oacc[dblk], 0, 0, 0);
      }
    }
    __syncthreads();
  }

  // ---- write O^T / li to At[B,T,C] (bf16); d-groups of 4 are contiguous ----
  const float inv = 1.0f / li;
  const size_t rowbase = ((size_t)(b * 2048 + qg)) * 1024 + h * 64;
#pragma unroll
  for (int dblk = 0; dblk < 2; ++dblk)
#pragma unroll
    for (int grp = 0; grp < 4; ++grp) {
      ushort4 st;
      st.x = f2bf(oacc[dblk][grp * 4 + 0] * inv);
      st.y = f2bf(oacc[dblk][grp * 4 + 1] * inv);
      st.z = f2bf(oacc[dblk][grp * 4 + 2] * inv);
      st.w = f2bf(oacc[dblk][grp * 4 + 3] * inv);
      *(ushort4*)((u16*)out + rowbase + dblk * 32 + grp * 8 + hl * 4) = st;
    }
}

// ---------------------------------------------------------------------------
__global__ __launch_bounds__(256) void outproj_kernel(const u16* __restrict__ attn,
                                                      const u16* __restrict__ Wob,
                                                      const float* __restrict__ bo,
                                                      float* __restrict__ out) {
  __shared__ __align__(16) u16 lA[128 * 64];
  __shared__ __align__(16) u16 lB[128 * 64];
  const int m0 = blockIdx.y * 128, n0 = blockIdx.x * 128;
  f32x4 acc[4][4];
  gemm_tile(attn, Wob, m0, n0, lA, lB, acc);
  const int tid = threadIdx.x, l = tid & 63;
  const int wr = tid >> 7, wc = (tid >> 6) & 1;
#pragma unroll
  for (int m = 0; m < 4; ++m)
#pragma unroll
    for (int n = 0; n < 4; ++n)
#pragma unroll
      for (int jr = 0; jr < 4; ++jr) {
        int gr = m0 + wr * 64 + m * 16 + ((l >> 4) << 2) + jr;
        int gc = n0 + wc * 64 + n * 16 + (l & 15);
        out[(size_t)gr * 1024 + gc] = acc[m][n][jr] + bo[gc];
      }
}

// ---------------------------------------------------------------------------
extern "C" void kernel_launch(void* const* d_in, const int* in_sizes, int n_in,
                              void* d_out, int out_size, void* d_ws, size_t ws_size,
                              hipStream_t stream) {
  const float* x  = (const float*)d_in[0];
  const float* Wq = (const float*)d_in[1];
  const float* bq = (const float*)d_in[2];
  const float* Wk = (const float*)d_in[3];
  const float* bk = (const float*)d_in[4];
  const float* Wv = (const float*)d_in[5];
  const float* bv = (const float*)d_in[6];
  const float* Wo = (const float*)d_in[7];
  const float* bo = (const float*)d_in[8];
  float* out = (float*)d_out;

  char* ws = (char*)d_ws;
  u16* xb  = (u16*)(ws);                          // 8 MB
  u16* Wqb = (u16*)(ws + (8ull << 20));           // 2 MB
  u16* Wkb = (u16*)(ws + (10ull << 20));          // 2 MB
  u16* Wvb = (u16*)(ws + (12ull << 20));          // 2 MB
  u16* Wob = (u16*)(ws + (14ull << 20));          // 2 MB
  u16* Qr  = (u16*)(ws + (16ull << 20));          // 8 MB  [B,H,T,D] (pre-scaled)
  u16* Kr  = (u16*)(ws + (24ull << 20));          // 8 MB  [B,H,T,D]
  u16* Vt  = (u16*)(ws + (32ull << 20));          // 8 MB  [B,H,D,T]
  u16* At  = (u16*)(ws + (40ull << 20));          // 8 MB  attn out bf16 [B,T,C]
  float* tab = (float*)(ws + (48ull << 20));      // 512 KB rope table

  cvt_kernel<<<dim3(4096), dim3(256), 0, stream>>>(x, xb, 1048576);
  cvt_kernel<<<dim3(1024), dim3(256), 0, stream>>>(Wq, Wqb, 262144);
  cvt_kernel<<<dim3(1024), dim3(256), 0, stream>>>(Wk, Wkb, 262144);
  cvt_kernel<<<dim3(1024), dim3(256), 0, stream>>>(Wv, Wvb, 262144);
  cvt_kernel<<<dim3(1024), dim3(256), 0, stream>>>(Wo, Wob, 262144);
  rope_table_kernel<<<dim3(256), dim3(256), 0, stream>>>(tab);

  qkv_kernel<<<dim3(8, 32, 3), dim3(256), 0, stream>>>(xb, Wqb, Wkb, Wvb, bq, bk, bv,
                                                       tab, Qr, Kr, Vt);
  attn_kernel<<<dim3(1024), dim3(128), 0, stream>>>(Qr, Kr, Vt, At);
  outproj_kernel<<<dim3(8, 32), dim3(256), 0, stream>>>(At, Wob, bo, out);
}